// Round 1
// baseline (73.752 us; speedup 1.0000x reference)
//
#include <hip/hip_runtime.h>

// out[b,i] = relu( max_{j=1..64}( hf_pad[b,i+j] - j ) - hf[b,i] )
// With g[k] = hf_pad[k] - k  (hf_pad[k] = -1000 for k >= N):
//   out[i] = relu( max_{k=i+1..i+64} g[k]  -  g[i] )
// Window size 64 == wave size: two-scan block decomposition.
//   For i = 64*b + lane:  maxwin = max( suffmax_b[lane+1], prefmax_{b+1}[lane] )

#define N_COLS 4096
#define BPW 8                         // 64-blocks per wave
#define WAVES_PER_WG 4
#define WG_COVER (BPW * 64 * WAVES_PER_WG)   // 2048 elements per workgroup
#define NEG_INF (-3.0e38f)

__global__ __launch_bounds__(256) void slide_max_kernel(
    const float* __restrict__ hf, float* __restrict__ out) {
  const int lane = threadIdx.x & 63;
  const int wave = threadIdx.x >> 6;
  const int segsPerRow = N_COLS / WG_COVER;          // 2
  const int row = blockIdx.x / segsPerRow;
  const int seg = blockIdx.x % segsPerRow;
  const int base = seg * WG_COVER + wave * (BPW * 64);

  const float* rowp = hf + (size_t)row * N_COLS;
  float* outp = out + (size_t)row * N_COLS;

  // Preload g for BPW+1 blocks (one lookahead block for the prefix scan).
  float g[BPW + 1];
#pragma unroll
  for (int t = 0; t <= BPW; ++t) {
    int k = base + t * 64 + lane;
    float h = (k < N_COLS) ? rowp[k] : -1000.0f;   // right-pad sentinel
    g[t] = h - (float)k;
  }

#pragma unroll
  for (int blk = 0; blk < BPW; ++blk) {
    // inclusive suffix-max scan of current block (Hillis-Steele)
    float suf = g[blk];
#pragma unroll
    for (int d = 1; d < 64; d <<= 1) {
      float t = __shfl_down(suf, d);   // out-of-range lanes: own value (no-op for max)
      suf = fmaxf(suf, t);
    }
    // inclusive prefix-max scan of next block
    float pre = g[blk + 1];
#pragma unroll
    for (int d = 1; d < 64; d <<= 1) {
      float t = __shfl_up(pre, d);     // out-of-range lanes: own value (no-op for max)
      pre = fmaxf(pre, t);
    }
    // window [i+1, i+64]: suffix of own block starting at lane+1 (empty at lane 63)
    // plus prefix of next block through `lane`
    float s = __shfl_down(suf, 1);
    if (lane == 63) s = NEG_INF;
    float m = fmaxf(s, pre);
    float r = fmaxf(m - g[blk], 0.0f);
    outp[base + blk * 64 + lane] = r;
  }
}

extern "C" void kernel_launch(void* const* d_in, const int* in_sizes, int n_in,
                              void* d_out, int out_size, void* d_ws, size_t ws_size,
                              hipStream_t stream) {
  const float* hf = (const float*)d_in[0];
  float* out = (float*)d_out;
  const int total = in_sizes[0];
  const int rows = total / N_COLS;                 // 1024
  const int grid = rows * (N_COLS / WG_COVER);     // 2048 workgroups
  slide_max_kernel<<<grid, 256, 0, stream>>>(hf, out);
}

// Round 2
// 68.132 us; speedup vs baseline: 1.0825x; 1.0825x over previous
//
#include <hip/hip_runtime.h>

// out[b,i] = relu( max_{j=1..64}( hf_pad[b,i+j] - j ) - hf[b,i] )
// With g[k] = hf_pad[k] - k:  out[i] = relu( max_{k=i+1..i+64} g[k] - g[i] )
//
// Register-transposed Gil-Werman: each lane owns 8 CONSECUTIVE elements
// (chunk of 512 per wave). Window (i, i+64] at lane L pos t decomposes as:
//   own-lane suffix  suf[t+1..7]
// + full lanes L+1..L+7 (aggregate sliding max via clamped doubling)
// + lane L+8 prefix pre[0..t]            (lanes 0..55)
// or, for lanes 56..63 (window crosses chunk end):
// + lanes L+1..63 aggregates (tail) + halo prefix hp[0..8*(L-56)+t]
// Only 26 wave64 shuffles per 512 outputs (vs 104 in the block-scan version).

#define N_COLS 4096
#define CHUNK 512
#define NEG_INF (-3.0e38f)

__global__ __launch_bounds__(256) void slide_max_kernel(
    const float* __restrict__ hf, float* __restrict__ out) {
  const int lane = threadIdx.x & 63;
  const int wid = (blockIdx.x << 2) | (threadIdx.x >> 6);  // global wave id
  const int row = wid >> 3;                                // 8 chunks per row
  const int chunk = wid & 7;
  const int base = chunk * CHUNK;

  const float* rowp = hf + (size_t)row * N_COLS;
  float* outp = out + (size_t)row * N_COLS;

  // ---- load 8 consecutive floats per lane (two dwordx4), compute g ----
  const float4* rp4 = (const float4*)(rowp + base);  // base % 4 == 0
  float4 v0 = rp4[2 * lane];
  float4 v1 = rp4[2 * lane + 1];
  float x[8] = {v0.x, v0.y, v0.z, v0.w, v1.x, v1.y, v1.z, v1.w};
  const float kf = (float)(base + 8 * lane);
#pragma unroll
  for (int t = 0; t < 8; ++t) x[t] -= (kf + (float)t);

  // ---- halo element base+512+lane (1/lane, transposed) ----
  const int hk = base + CHUNK + lane;
  const float hh = (hk < N_COLS) ? rowp[hk] : -1000.0f;  // row-end sentinel
  const float gh = hh - (float)hk;

  // ---- per-lane serial prefix/suffix max scans ----
  float pre[8], suf[8];
  pre[0] = x[0];
#pragma unroll
  for (int t = 1; t < 8; ++t) pre[t] = fmaxf(pre[t - 1], x[t]);
  suf[7] = x[7];
#pragma unroll
  for (int t = 6; t >= 0; --t) suf[t] = fmaxf(suf[t + 1], x[t]);
  const float m = pre[7];  // lane aggregate

  // ---- clamped doubling over lane aggregates ----
  // w4[L] = max(m[L .. min(L+3,63)])  (shfl_down OOB returns own -> clamp)
  const float w2 = fmaxf(m, __shfl_down(m, 1));
  const float w4 = fmaxf(w2, __shfl_down(w2, 2));
  const float a = __shfl_down(w4, 1);  // max(m[L+1..min(L+4,63)]), valid L<=62
  const float b = __shfl_down(w4, 4);  // max(m[L+4..min(L+7,63)]), valid L<=59
  const float midA = fmaxf(a, b);      // lanes <=55: max(m[L+1..L+7])
  // lanes >=56: tail = max(m[L+1..63])
  const float tail = (lane <= 59) ? fmaxf(a, b)
                   : (lane <= 62) ? a
                                  : NEG_INF;

  // ---- prefixes of lane L+8 ----
  float preN[8];
#pragma unroll
  for (int t = 0; t < 8; ++t) preN[t] = __shfl_down(pre[t], 8);

  // ---- halo prefix scan across lanes (inclusive max-scan) ----
  float hp = gh;
#pragma unroll
  for (int d = 1; d < 64; d <<= 1) hp = fmaxf(hp, __shfl_up(hp, d));

  const bool hiLane = (lane >= 56);
  const int hidx = (lane & 7) << 3;  // halo prefix base index for hi lanes
  const float second = hiLane ? tail : midA;

  // ---- combine + relu + store ----
  float o[8];
#pragma unroll
  for (int t = 0; t < 8; ++t) {
    const float third_hi = __shfl(hp, hidx + t);  // bpermute; ignored lo lanes
    const float third = hiLane ? third_hi : preN[t];
    const float sufs = (t < 7) ? suf[t + 1] : NEG_INF;
    const float mw = fmaxf(fmaxf(sufs, second), third);
    o[t] = fmaxf(mw - x[t], 0.0f);
  }
  float4* op4 = (float4*)(outp + base);
  op4[2 * lane] = make_float4(o[0], o[1], o[2], o[3]);
  op4[2 * lane + 1] = make_float4(o[4], o[5], o[6], o[7]);
}

extern "C" void kernel_launch(void* const* d_in, const int* in_sizes, int n_in,
                              void* d_out, int out_size, void* d_ws, size_t ws_size,
                              hipStream_t stream) {
  const float* hf = (const float*)d_in[0];
  float* out = (float*)d_out;
  const int total = in_sizes[0];
  const int rows = total / N_COLS;                   // 1024
  const int waves = rows * (N_COLS / CHUNK);         // 8192 waves
  const int grid = waves / 4;                        // 4 waves per 256-thread WG
  slide_max_kernel<<<grid, 256, 0, stream>>>(hf, out);
}